// Round 2
// baseline (601.551 us; speedup 1.0000x reference)
//
#include <hip/hip_runtime.h>

// Masked inclusive cumsum along rows: out[r, :] = cumsum(where(mask, x, 0), axis=1)
// ROWS=2048, N=32768.
//
// R3: single-pass chained scan ("decoupled lookback lite").
// R2 (1024-thread row-per-block) was structure-bound: 2048-thread/CU cap ->
// ~1 resident block/CU, read-burst/scan/write-burst serialized, HBM 38%.
// Now: 8 segments/row x 256-thread blocks (16384 blocks, ~56 VGPR ->
// 8 blocks/CU). Grid is SEGMENT-MAJOR: all seg-0 blocks dispatch first, so a
// block's predecessor (lower block ID, same row) has already published its
// inclusive prefix when we poll -> near-zero spin, no deadlock (waits only on
// lower IDs; CP dispatches in ID order).
//
// Cross-block handoff: one 64-bit word per (seg,row) in d_ws:
//   [63:32] = ready flag (1), [31:0] = float bits of inclusive row prefix.
// Payload+flag share one atom -> relaxed agent-scope atomics suffice.
// d_ws flags are zeroed by hipMemsetAsync on every launch (capture-legal),
// so re-poisoned/stale workspaces are harmless.
//
// R4: compile fix — __builtin_nontemporal_store needs a native vector type,
// not HIP's float4 class; store via ext_vector_type(4) float (same layout).

#define ROWS    2048
#define NCOL    32768
#define THREADS 256
#define TILES   4
#define SEGLEN  (THREADS * TILES * 4)   // 4096 elements per segment
#define NSEG    (NCOL / SEGLEN)         // 8 segments per row
#define NCHK    (THREADS * TILES)       // 1024 float4-chunk sums per block

static_assert(ROWS == 2048, "seg/row decode uses >>11");
static_assert(NSEG * SEGLEN == NCOL, "exact tiling");

typedef float floatx4 __attribute__((ext_vector_type(4)));
static_assert(sizeof(floatx4) == sizeof(float4), "layout match");

__global__ __launch_bounds__(THREADS, 8) void masked_cumsum_lookback(
    const float* __restrict__ x,
    const int*   __restrict__ mask,
    float*       __restrict__ out,
    unsigned long long* __restrict__ flags)
{
    const int bid = blockIdx.x;
    const int seg = bid >> 11;            // segment-major: seg = bid / ROWS
    const int row = bid & (ROWS - 1);

    const size_t base = (size_t)row * NCOL + (size_t)seg * SEGLEN;
    const float4* __restrict__ xs = (const float4*)(x + base);
    const int4*   __restrict__ ms = (const int4*)(mask + base);
    floatx4*      __restrict__ os = (floatx4*)(out + base);

    const int tid  = threadIdx.x;
    const int lane = tid & 63;
    const int wave = tid >> 6;

    // Padded chunk-sum array: chunk c lives at c + (c>>3).
    __shared__ float csum[NCHK + NCHK / 8];
    __shared__ float wtot[THREADS / 64];
    __shared__ float rowoff;

    // ---- Phase A: load segment (8 independent 16B loads), mask, chunk prefix
    float4 xv[TILES];
    int4   mv[TILES];
    #pragma unroll
    for (int t = 0; t < TILES; ++t) {
        xv[t] = xs[t * THREADS + tid];
        mv[t] = ms[t * THREADS + tid];
    }

    float4 p[TILES];   // per-chunk inclusive prefixes
    #pragma unroll
    for (int t = 0; t < TILES; ++t) {
        float a0 = mv[t].x ? xv[t].x : 0.0f;
        float a1 = mv[t].y ? xv[t].y : 0.0f;
        float a2 = mv[t].z ? xv[t].z : 0.0f;
        float a3 = mv[t].w ? xv[t].w : 0.0f;
        p[t].x = a0;
        p[t].y = p[t].x + a1;
        p[t].z = p[t].y + a2;
        p[t].w = p[t].z + a3;
        int c = t * THREADS + tid;
        csum[c + (c >> 3)] = p[t].w;
    }
    __syncthreads();

    // ---- Phase B: block scan over 1024 chunk sums.
    // Thread j owns chunks 4j..4j+3 (padded LDS, <=2-3 way aliasing, cheap).
    float s[TILES];
    float run = 0.0f;
    const int c0 = tid * TILES;
    #pragma unroll
    for (int k = 0; k < TILES; ++k) {
        int c = c0 + k;
        run += csum[c + (c >> 3)];
        s[k] = run;
    }

    // Wave-64 inclusive scan of thread totals
    float sc = run;
    #pragma unroll
    for (int d = 1; d < 64; d <<= 1) {
        float o = __shfl_up(sc, d);
        if (lane >= d) sc += o;
    }
    if (lane == 63) wtot[wave] = sc;
    __syncthreads();

    float woff = 0.0f;
    #pragma unroll
    for (int w = 0; w < THREADS / 64; ++w)
        woff += (w < wave) ? wtot[w] : 0.0f;

    const float thr_excl = woff + (sc - run);  // exclusive prefix of chunk c0

    // Write exclusive chunk offsets back (overlaps with thread 0's lookback)
    #pragma unroll
    for (int k = 0; k < TILES; ++k) {
        int c = c0 + k;
        csum[c + (c >> 3)] = thr_excl + (k ? s[k - 1] : 0.0f);
    }

    // ---- Lookback: thread 0 fetches predecessor's inclusive prefix,
    // publishes own. Packed {flag|floatbits} -> relaxed atomics are enough.
    if (tid == 0) {
        float agg = 0.0f;
        #pragma unroll
        for (int w = 0; w < THREADS / 64; ++w) agg += wtot[w];

        float pre = 0.0f;
        if (seg > 0) {
            const unsigned long long* slot = flags + (size_t)(seg - 1) * ROWS + row;
            unsigned long long v =
                __hip_atomic_load(slot, __ATOMIC_RELAXED, __HIP_MEMORY_SCOPE_AGENT);
            while (!(v >> 32)) {
                __builtin_amdgcn_s_sleep(1);
                v = __hip_atomic_load(slot, __ATOMIC_RELAXED, __HIP_MEMORY_SCOPE_AGENT);
            }
            pre = __uint_as_float((unsigned)v);
        }
        if (seg < NSEG - 1) {
            unsigned long long pk =
                (1ULL << 32) | (unsigned long long)__float_as_uint(pre + agg);
            __hip_atomic_store(flags + (size_t)seg * ROWS + row, pk,
                               __ATOMIC_RELAXED, __HIP_MEMORY_SCOPE_AGENT);
        }
        rowoff = pre;
    }
    __syncthreads();

    // ---- Phase C: add offsets, nontemporal store (keep x/mask lines in L3)
    const float ro = rowoff;
    #pragma unroll
    for (int t = 0; t < TILES; ++t) {
        int c = t * THREADS + tid;
        float off = csum[c + (c >> 3)] + ro;
        floatx4 o = { off + p[t].x, off + p[t].y, off + p[t].z, off + p[t].w };
        __builtin_nontemporal_store(o, &os[t * THREADS + tid]);
    }
}

extern "C" void kernel_launch(void* const* d_in, const int* in_sizes, int n_in,
                              void* d_out, int out_size, void* d_ws, size_t ws_size,
                              hipStream_t stream) {
    const float* x    = (const float*)d_in[0];
    const int*   mask = (const int*)d_in[1];
    float*       out  = (float*)d_out;
    unsigned long long* flags = (unsigned long long*)d_ws;

    // Zero the ready flags every launch (capture-legal async op).
    (void)hipMemsetAsync(d_ws, 0,
                         (size_t)NSEG * ROWS * sizeof(unsigned long long), stream);

    masked_cumsum_lookback<<<ROWS * NSEG, THREADS, 0, stream>>>(x, mask, out, flags);
}

// Round 3
// 591.999 us; speedup vs baseline: 1.0161x; 1.0161x over previous
//
#include <hip/hip_runtime.h>

// Masked inclusive cumsum along rows: out[r, :] = cumsum(where(mask, x, 0), axis=1)
// ROWS=2048, N=32768.
//
// R3/R4: single-pass chained scan ("decoupled lookback lite"), 8 segments/row,
// 256-thread blocks, segment-major grid (predecessor always dispatched first).
// Cross-block handoff: {flag<<32 | float bits} in one 64-bit word -> relaxed
// agent-scope atomics. Flags zeroed by hipMemsetAsync each launch.
//
// R5: codegen fix. R4 came back with VGPR_Count=20 -> compiler sank the
// Phase-A loads into a serial chain and re-issued them in Phase C
// (rematerialization), killing memory-level parallelism (HBM 2.52 TB/s).
// Fix: keep-alive asm on all loaded values (forces all 16 loads in flight
// AND forbids re-loading them from memory later), launch_bounds(256,6) so
// the ~58 live VGPRs can't spill (budget 85), plain float4 stores (NT bought
// nothing in R4).

#define ROWS    2048
#define NCOL    32768
#define THREADS 256
#define TILES   4
#define SEGLEN  (THREADS * TILES * 4)   // 4096 elements per segment
#define NSEG    (NCOL / SEGLEN)         // 8 segments per row
#define NCHK    (THREADS * TILES)       // 1024 float4-chunk sums per block

static_assert(ROWS == 2048, "seg/row decode uses >>11");
static_assert(NSEG * SEGLEN == NCOL, "exact tiling");

__global__ __launch_bounds__(THREADS, 6) void masked_cumsum_lookback(
    const float* __restrict__ x,
    const int*   __restrict__ mask,
    float*       __restrict__ out,
    unsigned long long* __restrict__ flags)
{
    const int bid = blockIdx.x;
    const int seg = bid >> 11;            // segment-major: seg = bid / ROWS
    const int row = bid & (ROWS - 1);

    const size_t base = (size_t)row * NCOL + (size_t)seg * SEGLEN;
    const float4* __restrict__ xs = (const float4*)(x + base);
    const int4*   __restrict__ ms = (const int4*)(mask + base);
    float4*       __restrict__ os = (float4*)(out + base);

    const int tid  = threadIdx.x;
    const int lane = tid & 63;
    const int wave = tid >> 6;

    // Padded chunk-sum array: chunk c lives at c + (c>>3).
    __shared__ float csum[NCHK + NCHK / 8];
    __shared__ float wtot[THREADS / 64];
    __shared__ float rowoff;

    // ---- Phase A: load segment — 16 independent 16B loads, all in flight.
    float4 xv[TILES];
    int4   mv[TILES];
    #pragma unroll
    for (int t = 0; t < TILES; ++t) {
        xv[t] = xs[t * THREADS + tid];
        mv[t] = ms[t * THREADS + tid];
    }
    // Keep-alive: forces every load issued before this point (full MLP) and
    // marks the values as asm-modified, so the compiler can NEVER re-load
    // them from global memory in Phase C (the R4 remat pessimization).
    asm volatile("" :
        "+v"(xv[0].x), "+v"(xv[0].y), "+v"(xv[0].z), "+v"(xv[0].w),
        "+v"(xv[1].x), "+v"(xv[1].y), "+v"(xv[1].z), "+v"(xv[1].w),
        "+v"(xv[2].x), "+v"(xv[2].y), "+v"(xv[2].z), "+v"(xv[2].w),
        "+v"(xv[3].x), "+v"(xv[3].y), "+v"(xv[3].z), "+v"(xv[3].w));
    asm volatile("" :
        "+v"(mv[0].x), "+v"(mv[0].y), "+v"(mv[0].z), "+v"(mv[0].w),
        "+v"(mv[1].x), "+v"(mv[1].y), "+v"(mv[1].z), "+v"(mv[1].w),
        "+v"(mv[2].x), "+v"(mv[2].y), "+v"(mv[2].z), "+v"(mv[2].w),
        "+v"(mv[3].x), "+v"(mv[3].y), "+v"(mv[3].z), "+v"(mv[3].w));

    float4 p[TILES];   // per-chunk inclusive prefixes
    #pragma unroll
    for (int t = 0; t < TILES; ++t) {
        float a0 = mv[t].x ? xv[t].x : 0.0f;
        float a1 = mv[t].y ? xv[t].y : 0.0f;
        float a2 = mv[t].z ? xv[t].z : 0.0f;
        float a3 = mv[t].w ? xv[t].w : 0.0f;
        p[t].x = a0;
        p[t].y = p[t].x + a1;
        p[t].z = p[t].y + a2;
        p[t].w = p[t].z + a3;
        int c = t * THREADS + tid;
        csum[c + (c >> 3)] = p[t].w;
    }
    __syncthreads();

    // ---- Phase B: block scan over 1024 chunk sums.
    // Thread j owns chunks 4j..4j+3 (private slots, no cross-thread hazard).
    float s[TILES];
    float run = 0.0f;
    const int c0 = tid * TILES;
    #pragma unroll
    for (int k = 0; k < TILES; ++k) {
        int c = c0 + k;
        run += csum[c + (c >> 3)];
        s[k] = run;
    }

    // Wave-64 inclusive scan of thread totals
    float sc = run;
    #pragma unroll
    for (int d = 1; d < 64; d <<= 1) {
        float o = __shfl_up(sc, d);
        if (lane >= d) sc += o;
    }
    if (lane == 63) wtot[wave] = sc;
    __syncthreads();

    float woff = 0.0f;
    #pragma unroll
    for (int w = 0; w < THREADS / 64; ++w)
        woff += (w < wave) ? wtot[w] : 0.0f;

    const float thr_excl = woff + (sc - run);  // exclusive prefix of chunk c0

    // Write exclusive chunk offsets back to the private slots.
    #pragma unroll
    for (int k = 0; k < TILES; ++k) {
        int c = c0 + k;
        csum[c + (c >> 3)] = thr_excl + (k ? s[k - 1] : 0.0f);
    }

    // ---- Lookback: thread 0 fetches predecessor's inclusive prefix,
    // publishes own. Packed {flag|floatbits} -> relaxed atomics suffice.
    if (tid == 0) {
        float agg = 0.0f;
        #pragma unroll
        for (int w = 0; w < THREADS / 64; ++w) agg += wtot[w];

        float pre = 0.0f;
        if (seg > 0) {
            const unsigned long long* slot = flags + (size_t)(seg - 1) * ROWS + row;
            unsigned long long v =
                __hip_atomic_load(slot, __ATOMIC_RELAXED, __HIP_MEMORY_SCOPE_AGENT);
            while (!(v >> 32)) {
                __builtin_amdgcn_s_sleep(1);
                v = __hip_atomic_load(slot, __ATOMIC_RELAXED, __HIP_MEMORY_SCOPE_AGENT);
            }
            pre = __uint_as_float((unsigned)v);
        }
        if (seg < NSEG - 1) {
            unsigned long long pk =
                (1ULL << 32) | (unsigned long long)__float_as_uint(pre + agg);
            __hip_atomic_store(flags + (size_t)seg * ROWS + row, pk,
                               __ATOMIC_RELAXED, __HIP_MEMORY_SCOPE_AGENT);
        }
        rowoff = pre;
    }
    __syncthreads();

    // ---- Phase C: add offsets, store (plain float4 — NT gained nothing)
    const float ro = rowoff;
    #pragma unroll
    for (int t = 0; t < TILES; ++t) {
        int c = t * THREADS + tid;
        float off = csum[c + (c >> 3)] + ro;
        os[t * THREADS + tid] =
            make_float4(off + p[t].x, off + p[t].y, off + p[t].z, off + p[t].w);
    }
}

extern "C" void kernel_launch(void* const* d_in, const int* in_sizes, int n_in,
                              void* d_out, int out_size, void* d_ws, size_t ws_size,
                              hipStream_t stream) {
    const float* x    = (const float*)d_in[0];
    const int*   mask = (const int*)d_in[1];
    float*       out  = (float*)d_out;
    unsigned long long* flags = (unsigned long long*)d_ws;

    // Zero the ready flags every launch (capture-legal async op).
    (void)hipMemsetAsync(d_ws, 0,
                         (size_t)NSEG * ROWS * sizeof(unsigned long long), stream);

    masked_cumsum_lookback<<<ROWS * NSEG, THREADS, 0, stream>>>(x, mask, out, flags);
}